// Round 8
// baseline (194.458 us; speedup 1.0000x reference)
//
#include <hip/hip_runtime.h>

typedef __attribute__((ext_vector_type(8))) short short8;   // 8 x bf16 (4 VGPR)
typedef __attribute__((ext_vector_type(4))) float f32x4;

#define Bsz 4
#define Cin 256
#define Cout 256
#define Hh 64
#define Ww 64
#define HW 4096
#define NG 16
#define EPSV 1e-5f

#define CSTR 40        // col LDS row stride in ushorts: 32 data + 8 pad = 80 B
#define SPAN 12        // staged input rows per window
#define ROWB 4112      // staged row stride bytes: 16 pairs x 64 px x 4B + 16 pad

// ---- dcn dynamic LDS layout (bytes) ----
#define OFF_IN   0
#define SZ_IN    (SPAN * ROWB)         // 49344: bf16 pair-plane window
#define OFF_COL  49344                 // 9 x 32 x CSTR ushorts = 23040 (9 taps)
#define OFF_CTL  72384                 // ymin/ymax
#define SMEM_BYTES 72400               // x2 blocks = 144800 <= 160 KiB/CU

static __device__ __forceinline__ unsigned f2bf(float f) {
    unsigned u = __float_as_uint(f);
    return (u + 0x7fffu + ((u >> 16) & 1u)) >> 16;   // RNE bf16
}

static __device__ __forceinline__ float2 ld8(const float* p) {
    float2 v;
    __builtin_memcpy(&v, p, 8);   // 8B load (global or LDS)
    return v;
}

#define BLO(u) __uint_as_float((u) << 16)          // bf16 in low half -> f32
#define BHI(u) __uint_as_float((u) & 0xffff0000u)  // bf16 in high half -> f32

// ---------------------------------------------------------------------------
// Kernel 1 (fused prep):
//  blocks [0,256): input transpose NCHW f32 -> bf16 pair-plane
//      inT word(u32 = ch2p lo | ch2p+1 hi) idx = ((b*64+y)*128 + pr)*64 + x
//  blocks [256,1408): weight reorder w[o][c][kk] -> bf16 wtb[ks][o][32],
//      ks = kk*8 + c/32;  + zero GN stats accumulators.
// ---------------------------------------------------------------------------
__launch_bounds__(512)
__global__ void prep_kernel(const float* __restrict__ in,
                            const float* __restrict__ w,
                            unsigned* __restrict__ inT,
                            ushort* __restrict__ wtb,
                            float* __restrict__ stats) {
    const int t  = threadIdx.x;
    const int bx = blockIdx.x;
    if (bx < 256) {                    // ---- transpose ----
        const int b = bx >> 6, y = bx & 63;
        const int x = t & 63, w8 = t >> 6;
        const float* src = in + (size_t)b * 256 * HW + y * 64 + x;
        unsigned* dst = inT + ((size_t)(b * 64 + y) * 128) * 64 + x;
#pragma unroll
        for (int it = 0; it < 16; it++) {
            const int pr = w8 + it * 8;
            const float a0 = src[(size_t)(2 * pr) * HW];
            const float a1 = src[(size_t)(2 * pr + 1) * HW];
            dst[(size_t)pr * 64] = f2bf(a0) | (f2bf(a1) << 16);
        }
        return;
    }
    if (bx == 256 && t < 128) stats[t] = 0.f;
    const int i = (bx - 256) * 512 + t;                // over 589824
    if (i >= 72 * 256 * 32) return;
    const int cl = i & 31;
    const int o  = (i >> 5) & 255;
    const int ks = i >> 13;
    const int c  = ((ks & 7) << 5) | cl;
    const int kk = ks >> 3;
    wtb[i] = (ushort)f2bf(w[((size_t)o * Cin + c) * 9 + kk]);
}

// ---------------------------------------------------------------------------
// Kernel 2: fused deformable sampling + bf16 MFMA conv + GN partial stats.
// CHANGE vs prev: tap tables moved LDS -> REGISTERS. Each thread computes the
// 9 taps of its own pixel once (redundant across waves, trivial), packs the
// two window-relative byte offsets into one u32 (u16|u16<<16, max 45485) and
// keeps the 4 fold weights in f32 regs. The gather phase is now 18
// independent ds_read_b64 with register addresses -> one LDS round-trip per
// phase instead of ~2 per tap (in-order lgkmcnt chain removed). LDS reads
// per thread-chunk: 45 -> 27; tables no longer re-read x8 chunks.
// Block: 512 threads (8 waves): N=32 px, M=256 Co; grid 512 (2 blocks/CU).
// ---------------------------------------------------------------------------
__launch_bounds__(512, 4)
__global__ void dcn_kernel(const float* __restrict__ in,
                           const unsigned* __restrict__ inT,
                           const float* __restrict__ offs,
                           const float* __restrict__ mask,
                           const ushort* __restrict__ wtb,
                           const float* __restrict__ bias,
                           float* __restrict__ out,
                           float* __restrict__ stats) {
    extern __shared__ char smem[];
    ushort* col  = (ushort*)(smem + OFF_COL);   // [9][32*CSTR]
    int*    s_ctl = (int*)(smem + OFF_CTL);     // [0]=ymin [1]=ymax

    const int t  = threadIdx.x;
    const int bx = blockIdx.x;
    // XCD swizzle: XCD q = bx&7 serves batch q>>1, h-half q&1 (L2 locality).
    const int q  = bx & 7, r = bx >> 3;
    const int b  = q >> 1;
    const int h  = ((q & 1) << 5) | (r >> 1);
    const int wb = (r & 1) << 5;           // x-half base: 0 or 32
    const int lane = t & 63;
    const int wv   = t >> 6;               // wave 0..7
    const int quad = lane >> 4;
    const int l15  = lane & 15;
    const int px   = lane & 31;            // pixel in half-row (gather role)
    const int hi   = lane >> 5;            // which channel-pair of the wave's 4ch
    const int proff = (2 * wv + hi) * 256; // pair-plane byte offset in window row
    const int pp   = wb + px;              // global x of my pixel

    if (t < 2) s_ctl[t] = (t == 0) ? 64 : -1;
    __syncthreads();

    // ---- per-thread tap compute: 9 taps of pixel pp (registers only) ----
    const float* ob = offs + (size_t)b * 18 * HW + h * Ww + pp;
    const float* mb = mask + (size_t)b * 9 * HW + h * Ww + pp;
    int ryc0[9], ryc1[9], rxb[9];
    float4 tw4[9];
    int my_min = 64, my_max = -1;
#pragma unroll
    for (int k = 0; k < 9; k++) {
        const float dy = ob[(2 * k) * HW];
        const float dx = ob[(2 * k + 1) * HW];
        const float m  = mb[k * HW];
        const float y = (float)h + (float)(k / 3 - 1) + dy;
        const float x = (float)pp + (float)(k % 3 - 1) + dx;
        const float y0f = floorf(y), x0f = floorf(x);
        const float ly = y - y0f, lx = x - x0f;
        const float hy = 1.f - ly, hx = 1.f - lx;
        const int y0 = (int)y0f, x0 = (int)x0f;
        const int yc0 = min(max(y0, 0), 63);
        const int yc1 = min(max(y0 + 1, 0), 63);
        const int xb  = min(max(x0, 0), 62);
        // col-remapped pair coefficients (corner validity folded):
        //   v.x = col[xb], v.y = col[xb+1]
        float ax = 0.f, ay = 0.f;
        if (x0 == xb) {                       // x0 in [0,62]: both corners in-row
            ax = hx;
            ay = lx;
        } else if (x0 < xb) {                 // x0 < 0
            ax = (x0 + 1 == 0) ? lx : 0.f;
        } else {                              // x0 > 62
            ay = (x0 == 63) ? hx : 0.f;
        }
        const float w0 = (y0 >= 0 && y0 < 64) ? m * hy : 0.f;
        const float w1 = (y0 + 1 >= 0 && y0 + 1 < 64) ? m * ly : 0.f;
        ryc0[k] = yc0; ryc1[k] = yc1; rxb[k] = xb;
        tw4[k] = make_float4(w0 * ax, w0 * ay, w1 * ax, w1 * ay);
        my_min = min(my_min, yc0);
        my_max = max(my_max, yc1);
    }
#pragma unroll
    for (int off = 32; off; off >>= 1) {
        my_min = min(my_min, __shfl_xor(my_min, off));
        my_max = max(my_max, __shfl_xor(my_max, off));
    }
    if (lane == 0) {
        atomicMin(&s_ctl[0], my_min);
        atomicMax(&s_ctl[1], my_max);
    }
    __syncthreads();

    const int ymin = s_ctl[0];
    const bool use_lds = (s_ctl[1] - ymin + 1) <= SPAN;

    // pack window-relative byte offsets (u16|u16): rel <= 11*4112+248 < 65536
    unsigned tad[9];
#pragma unroll
    for (int k = 0; k < 9; k++) {
        const unsigned r0 = (unsigned)((ryc0[k] - ymin) * ROWB + rxb[k] * 4);
        const unsigned r1 = (unsigned)((ryc1[k] - ymin) * ROWB + rxb[k] * 4);
        tad[k] = (r0 & 0xffffu) | (r1 << 16);   // hi garbage ok if !use_lds
    }

    f32x4 acc[2][2];
#pragma unroll
    for (int i = 0; i < 2; i++)
#pragma unroll
        for (int nt = 0; nt < 2; nt++) acc[i][nt] = (f32x4){0.f, 0.f, 0.f, 0.f};

    const float* inb = in + (size_t)b * Cin * HW;

    // Stage chunk cc: SPAN rows x 16 pair-planes x 64 px x 4B = 48 KB.
    // Per row: 16 planes contiguous in global (4 KB) = 4 linear 1KB segments.
#define STAGE(cc)                                                              \
    {                                                                          \
        _Pragma("unroll")                                                      \
        for (int i = 0; i < 6; i++) {                                          \
            const int g = wv * 6 + i;                                          \
            const int rr = g >> 2, seg = g & 3;                                \
            const int row = min(ymin + rr, 63);                                \
            const unsigned* src = inT +                                        \
                ((size_t)(b * 64 + row) * 128 + (cc) * 16) * 64 +              \
                seg * 256 + lane * 4;                                          \
            __builtin_amdgcn_global_load_lds(                                  \
                (const __attribute__((address_space(1))) void*)src,            \
                (__attribute__((address_space(3))) void*)(smem + OFF_IN +      \
                    rr * ROWB + seg * 1024),                                   \
                16, 0, 0);                                                     \
        }                                                                      \
    }

    // gather this thread's channel-pair for tap kk: register address + weights
#define GATHER_PUB_L(kk)                                                   \
    {                                                                      \
        const unsigned ad = tad[kk];                                       \
        const float4 tw = tw4[kk];                                         \
        const char* bp = smem + OFF_IN + proff;                            \
        const float2 f0 = ld8((const float*)(bp + (ad & 0xffffu)));        \
        const float2 f1 = ld8((const float*)(bp + (ad >> 16)));            \
        const unsigned u00 = __float_as_uint(f0.x);                        \
        const unsigned u01 = __float_as_uint(f0.y);                        \
        const unsigned u10 = __float_as_uint(f1.x);                        \
        const unsigned u11 = __float_as_uint(f1.y);                        \
        const float v0 = tw.x * BLO(u00) + tw.y * BLO(u01) +               \
                         tw.z * BLO(u10) + tw.w * BLO(u11);                \
        const float v1 = tw.x * BHI(u00) + tw.y * BHI(u01) +               \
                         tw.z * BHI(u10) + tw.w * BHI(u11);                \
        *(unsigned*)&col[(kk) * (32 * CSTR) + px * CSTR + (wv << 2) +      \
                         (hi << 1)] = f2bf(v0) | (f2bf(v1) << 16);         \
    }

#define FRAGS_MFMA(ks, kk)                                                     \
    {                                                                          \
        const ushort* wp =                                                     \
            wtb + ((size_t)((ks) * 256 + wv * 32 + l15)) * 32 + quad * 8;      \
        const short8 a0 = *(const short8*)wp;                                  \
        const short8 a1 = *(const short8*)(wp + 16 * 32);                      \
        short8 bfr[2];                                                         \
        _Pragma("unroll")                                                      \
        for (int nt = 0; nt < 2; nt++)                                         \
            bfr[nt] = *(const short8*)&col[(kk) * (32 * CSTR) +                \
                                           (nt * 16 + l15) * CSTR + quad * 8]; \
        _Pragma("unroll")                                                      \
        for (int nt = 0; nt < 2; nt++) {                                       \
            acc[0][nt] = __builtin_amdgcn_mfma_f32_16x16x32_bf16(              \
                a0, bfr[nt], acc[0][nt], 0, 0, 0);                             \
            acc[1][nt] = __builtin_amdgcn_mfma_f32_16x16x32_bf16(              \
                a1, bfr[nt], acc[1][nt], 0, 0, 0);                             \
        }                                                                      \
    }

    if (use_lds) {
        STAGE(0);
        __syncthreads();                 // window 0 staged (vmcnt drained)
#pragma unroll 1
        for (int cc = 0; cc < 8; cc++) {
            // ---- gather phase: 18 independent reg-addressed LDS loads ----
#pragma unroll
            for (int kk = 0; kk < 9; kk++) GATHER_PUB_L(kk);
            __syncthreads();             // A: col ready; window reads done
            if (cc < 7) STAGE(cc + 1);   // async overwrite of window
            // ---- MFMA phase: 9 taps, no barriers ----
#pragma unroll 3
            for (int kk = 0; kk < 9; kk++) FRAGS_MFMA(kk * 8 + cc, kk);
            __syncthreads();             // B: staging drained; col reads done
        }
    } else {
        // fallback (span > SPAN; ~never): recompute taps, gather global NCHW
#pragma unroll 1
        for (int cc = 0; cc < 8; cc++) {
#pragma unroll 1
            for (int kk = 0; kk < 9; kk++) {
                const float dy = ob[(2 * kk) * HW];
                const float dx = ob[(2 * kk + 1) * HW];
                const float m  = mb[kk * HW];
                const float y = (float)h + (float)(kk / 3 - 1) + dy;
                const float x = (float)pp + (float)(kk % 3 - 1) + dx;
                const float y0f = floorf(y), x0f = floorf(x);
                const float ly = y - y0f, lx = x - x0f;
                const float hy = 1.f - ly, hx = 1.f - lx;
                const int y0 = (int)y0f, x0 = (int)x0f;
                const int yc0 = min(max(y0, 0), 63);
                const int yc1 = min(max(y0 + 1, 0), 63);
                const int xb  = min(max(x0, 0), 62);
                float ax = 0.f, ay = 0.f;
                if (x0 == xb)      { ax = hx; ay = lx; }
                else if (x0 < xb)  { ax = (x0 + 1 == 0) ? lx : 0.f; }
                else               { ay = (x0 == 63) ? hx : 0.f; }
                const float w0 = (y0 >= 0 && y0 < 64) ? m * hy : 0.f;
                const float w1 = (y0 + 1 >= 0 && y0 + 1 < 64) ? m * ly : 0.f;
                const int adx = yc0 * 64 + xb, ady = yc1 * 64 + xb;
                const float* cb = inb + (size_t)(cc * 32 + wv * 4 + hi * 2) * HW;
                float vv[2];
#pragma unroll
                for (int j = 0; j < 2; j++) {
                    const float* pl = cb + j * HW;
                    const float2 g0 = ld8(pl + adx);
                    const float2 g1 = ld8(pl + ady);
                    vv[j] = (w0 * ax) * g0.x + (w0 * ay) * g0.y +
                            (w1 * ax) * g1.x + (w1 * ay) * g1.y;
                }
                *(unsigned*)&col[kk * (32 * CSTR) + px * CSTR + (wv << 2) +
                                 (hi << 1)] = f2bf(vv[0]) | (f2bf(vv[1]) << 16);
            }
            __syncthreads();
#pragma unroll 3
            for (int kk = 0; kk < 9; kk++) FRAGS_MFMA(kk * 8 + cc, kk);
            __syncthreads();
        }
    }
#undef STAGE
#undef GATHER_PUB_L
#undef FRAGS_MFMA

    // ---- epilogue: bias, store, GN partial stats ----
    float gs[2], gq[2];
#pragma unroll
    for (int i = 0; i < 2; i++) {
        float s = 0.f, qq = 0.f;
        const int ob2 = wv * 32 + i * 16 + quad * 4;
#pragma unroll
        for (int reg = 0; reg < 4; reg++) {
            const int o = ob2 + reg;
            const float bv = bias[o];
            float* op = out + ((size_t)(b * 256 + o)) * HW + h * Ww + wb + l15;
#pragma unroll
            for (int nt = 0; nt < 2; nt++) {
                const float v = acc[i][nt][reg] + bv;
                op[nt * 16] = v;
                s += v;
                qq += v * v;
            }
        }
        gs[i] = s; gq[i] = qq;
    }
#pragma unroll
    for (int off = 32; off; off >>= 1) {
        gs[0] += __shfl_xor(gs[0], off);
        gq[0] += __shfl_xor(gq[0], off);
        gs[1] += __shfl_xor(gs[1], off);
        gq[1] += __shfl_xor(gq[1], off);
    }
    if (lane == 0) {
#pragma unroll
        for (int i = 0; i < 2; i++) {
            const int g = wv * 2 + i;
            atomicAdd(&stats[((size_t)b * NG + g) * 2],     gs[i]);
            atomicAdd(&stats[((size_t)b * NG + g) * 2 + 1], gq[i]);
        }
    }
}

// ---------------------------------------------------------------------------
// Kernel 3: GN apply (mu/rsqrt from accumulated sums, in place)
// ---------------------------------------------------------------------------
__global__ void gn_apply_kernel(float* __restrict__ x, const float* __restrict__ stats,
                                const float* __restrict__ gamma,
                                const float* __restrict__ beta) {
    const int i = blockIdx.x * 256 + threadIdx.x;      // float4 idx, 1048576 total
    const int plane = i >> 10;                         // b*256 + o
    const int o = plane & 255;
    const int bg = plane >> 4;                         // b*16 + g
    const float s = stats[bg * 2], q = stats[bg * 2 + 1];
    const float inv_n = 1.f / 65536.f;
    const float mu = s * inv_n;
    const float var = q * inv_n - mu * mu;
    const float rs = rsqrtf(var + EPSV);
    const float ga = gamma[o] * rs;
    const float be = beta[o] - mu * ga;
    float4 v = ((float4*)x)[i];
    v.x = v.x * ga + be;
    v.y = v.y * ga + be;
    v.z = v.z * ga + be;
    v.w = v.w * ga + be;
    ((float4*)x)[i] = v;
}

// ---------------------------------------------------------------------------
extern "C" void kernel_launch(void* const* d_in, const int* in_sizes, int n_in,
                              void* d_out, int out_size, void* d_ws, size_t ws_size,
                              hipStream_t stream) {
    const float* input  = (const float*)d_in[0];
    const float* offset = (const float*)d_in[1];
    const float* maskp  = (const float*)d_in[2];
    const float* weight = (const float*)d_in[3];
    const float* bias   = (const float*)d_in[4];
    const float* gamma  = (const float*)d_in[5];
    const float* beta   = (const float*)d_in[6];
    float* out = (float*)d_out;

    ushort* wtb  = (ushort*)d_ws;                           // 1.18 MB
    float* stats = (float*)((char*)d_ws + (size_t)Cout * Cin * 9 * sizeof(ushort));
    unsigned* inT = (unsigned*)((char*)d_ws + 1180160);     // 8 MB bf16 pair-plane

    static int attr_done = 0;
    if (!attr_done) {
        hipFuncSetAttribute((const void*)dcn_kernel,
                            hipFuncAttributeMaxDynamicSharedMemorySize, SMEM_BYTES);
        attr_done = 1;
    }

    hipLaunchKernelGGL(prep_kernel, dim3(256 + 1152), dim3(512), 0, stream,
                       input, weight, inT, wtb, stats);
    hipLaunchKernelGGL(dcn_kernel, dim3(Bsz * Hh * 2), dim3(512), SMEM_BYTES, stream,
                       input, inT, offset, maskp, wtb, bias, out, stats);
    hipLaunchKernelGGL(gn_apply_kernel, dim3((Bsz * Cout * HW / 4) / 256), dim3(256), 0,
                       stream, out, stats, gamma, beta);
}